// Round 8
// baseline (199.413 us; speedup 1.0000x reference)
//
#include <hip/hip_runtime.h>
#include <stdint.h>

typedef float f32x4 __attribute__((ext_vector_type(4)));
typedef __bf16 bf16x8 __attribute__((ext_vector_type(8)));
typedef uint32_t u32a  __attribute__((may_alias));
typedef uint2    u2a   __attribute__((may_alias));
typedef uint4    u4a   __attribute__((may_alias));

#define VS 2064   // Vt row stride in elements (2048 + 16: breaks 4KB L2 aliasing)

__device__ __forceinline__ ushort f2b(float f) {
  uint32_t u = __builtin_bit_cast(uint32_t, f);
  u += 0x7FFFu + ((u >> 16) & 1u);   // round-to-nearest-even
  return (ushort)(u >> 16);
}
__device__ __forceinline__ uint32_t b16(uint32_t u) {  // fp32 bits -> bf16 bits (RNE)
  u += 0x7FFFu + ((u >> 16) & 1u);
  return u >> 16;
}

__device__ __forceinline__ bf16x8 ld_frag(const ushort* p) {
  u4a u = *(const u4a*)p;            // ds_read_b128 / global_load_dwordx4
  return __builtin_bit_cast(bf16x8, u);
}

// 8 fp32 -> 8 bf16 packed (two dwordx4 loads + RNE pack)
__device__ __forceinline__ u4a cvt8(const float* p) {
  u4a a = *(const u4a*)p, b = *(const u4a*)(p + 4), o;
  o.x = b16(a.x) | (b16(a.y) << 16);
  o.y = b16(a.z) | (b16(a.w) << 16);
  o.z = b16(b.x) | (b16(b.y) << 16);
  o.w = b16(b.z) | (b16(b.w) << 16);
  return o;
}

__device__ __forceinline__ void load_lds16(const void* g, void* l) {
  __builtin_amdgcn_global_load_lds(
      (const __attribute__((address_space(1))) uint32_t*)g,
      (__attribute__((address_space(3))) uint32_t*)l, 16, 0, 0);
}

// combine two packed bf16 pairs with weights w0,w1, repack
__device__ __forceinline__ uint32_t comb2(uint32_t a, uint32_t b, float w0, float w1) {
  float lo = __builtin_bit_cast(float, a << 16) * w0 +
             __builtin_bit_cast(float, b << 16) * w1;
  float hi = __builtin_bit_cast(float, a & 0xFFFF0000u) * w0 +
             __builtin_bit_cast(float, b & 0xFFFF0000u) * w1;
  return (uint32_t)f2b(lo) | ((uint32_t)f2b(hi) << 16);
}

// ---------------------------------------------------------------------------
// fp32 -> bf16 one-shot convert: x (3145728) then wq/wk/wv/wo (589824 each).
// ---------------------------------------------------------------------------
__global__ __launch_bounds__(256) void convert_kernel(
    const float* __restrict__ x,  const float* __restrict__ wq,
    const float* __restrict__ wk, const float* __restrict__ wv,
    const float* __restrict__ wo,
    ushort* __restrict__ xb,  ushort* __restrict__ wqb,
    ushort* __restrict__ wkb, ushort* __restrict__ wvb,
    ushort* __restrict__ wob)
{
  const size_t NX = 3145728, NW = 589824;
  size_t idx = ((size_t)blockIdx.x * 256 + threadIdx.x) * 8;
  const float* src; ushort* dst; size_t off;
  if      (idx < NX)          { src = x;  dst = xb;  off = idx; }
  else if (idx < NX + NW)     { src = wq; dst = wqb; off = idx - NX; }
  else if (idx < NX + 2 * NW) { src = wk; dst = wkb; off = idx - NX - NW; }
  else if (idx < NX + 3 * NW) { src = wv; dst = wvb; off = idx - NX - 2 * NW; }
  else                        { src = wo; dst = wob; off = idx - NX - 3 * NW; }
  *(u4a*)(dst + off) = cvt8(src + off);
}

// ---------------------------------------------------------------------------
// QKV: C[M,N]=A[M,K]*B[N,K]^T, bf16, fp32 acc. BM=128 BN=64 BK=32, 256 thr.
// grid (32, 12, 3): y-tile == one head. z: 0->Q (PRE-SCALED by 1/8),
// 1->K row-major; 2->V written transposed to Vt[b][h][dv][s] (stride VS).
// ---------------------------------------------------------------------------
__global__ __launch_bounds__(256) void gemm_qkv(
    const ushort* __restrict__ A,
    const ushort* __restrict__ B0, const ushort* __restrict__ B1,
    const ushort* __restrict__ B2,
    ushort* __restrict__ Qo, ushort* __restrict__ Ko, ushort* __restrict__ Vt,
    int M, int N, int K)
{
  const ushort* B = blockIdx.z == 0 ? B0 : (blockIdx.z == 1 ? B1 : B2);
  const int m0 = blockIdx.x * 128, n0 = blockIdx.y * 64;
  __shared__ ushort As[128 * 32];   // linear chunk order (global_load_lds layout)
  __shared__ ushort Bs[64 * 32];
  const int tid = threadIdx.x, wave = tid >> 6, lane = tid & 63;
  const int quad = lane >> 4, l16 = lane & 15;
  const int mw = (wave & 1) * 64, nw = (wave >> 1) * 32;
  f32x4 acc[4][2] = {};

  for (int k0 = 0; k0 < K; k0 += 32) {
    // A: 512 chunks of 16B (2/thread); B: 256 chunks (1/thread)
#pragma unroll
    for (int i = 0; i < 2; ++i) {
      int c = i * 256 + tid;
      load_lds16(A + (size_t)(m0 + (c >> 2)) * K + k0 + (c & 3) * 8,
                 As + (size_t)(i * 256 + wave * 64) * 8);
    }
    load_lds16(B + (size_t)(n0 + (tid >> 2)) * K + k0 + (tid & 3) * 8,
               Bs + (size_t)(wave * 64) * 8);
    __syncthreads();
    bf16x8 af[4], bfr[2];
#pragma unroll
    for (int i = 0; i < 4; ++i) af[i]  = ld_frag(As + (mw + i * 16 + l16) * 32 + quad * 8);
#pragma unroll
    for (int j = 0; j < 2; ++j) bfr[j] = ld_frag(Bs + (nw + j * 16 + l16) * 32 + quad * 8);
#pragma unroll
    for (int i = 0; i < 4; ++i)
#pragma unroll
      for (int j = 0; j < 2; ++j)
        acc[i][j] = __builtin_amdgcn_mfma_f32_16x16x32_bf16(af[i], bfr[j], acc[i][j], 0, 0, 0);
    __syncthreads();
  }
  // C/D layout: col=lane&15 (N), row=quad*4+reg (M)
  if (blockIdx.z < 2) {
    ushort* C = blockIdx.z == 0 ? Qo : Ko;
    const float sc = blockIdx.z == 0 ? 0.125f : 1.0f;  // fold 1/sqrt(dk) into Q
#pragma unroll
    for (int i = 0; i < 4; ++i)
#pragma unroll
      for (int j = 0; j < 2; ++j)
#pragma unroll
        for (int r = 0; r < 4; ++r) {
          int row = m0 + mw + i * 16 + quad * 4 + r;
          int col = n0 + nw + j * 16 + l16;
          C[(size_t)row * N + col] = f2b(acc[i][j][r] * sc);
        }
  } else {
    // Vt[b][h][dv][s] (stride VS): h == blockIdx.y, dv = col&63
#pragma unroll
    for (int i = 0; i < 4; ++i)
#pragma unroll
      for (int j = 0; j < 2; ++j) {
        int col = n0 + nw + j * 16 + l16;
        int h = col >> 6, dv = col & 63;
        int t = m0 + mw + i * 16 + quad * 4;
        int b = t >> 11, s = t & 2047;
        u2a pw;
        pw.x = (uint32_t)f2b(acc[i][j][0]) | ((uint32_t)f2b(acc[i][j][1]) << 16);
        pw.y = (uint32_t)f2b(acc[i][j][2]) | ((uint32_t)f2b(acc[i][j][3]) << 16);
        *(u2a*)(Vt + (((size_t)b * 12 + h) * 64 + dv) * VS + s) = pw;
      }
  }
}

// ---------------------------------------------------------------------------
// Output projection: C[M,N](fp32) = A[M,K](bf16)*B[N,K]^T(bf16).
// BM=BN=64, BK=32, 256 thr, grid (64,12) = 768 blocks (3/CU).
// ---------------------------------------------------------------------------
__global__ __launch_bounds__(256) void gemm_out(
    const ushort* __restrict__ A, const ushort* __restrict__ B,
    float* __restrict__ C, int M, int N, int K)
{
  const int m0 = blockIdx.x * 64, n0 = blockIdx.y * 64;
  __shared__ ushort As[64 * 32];
  __shared__ ushort Bs[64 * 32];
  const int tid = threadIdx.x, wave = tid >> 6, lane = tid & 63;
  const int quad = lane >> 4, l16 = lane & 15;
  const int mw = (wave & 1) * 32, nw = (wave >> 1) * 32;
  f32x4 acc[2][2] = {};

  for (int k0 = 0; k0 < K; k0 += 32) {
    load_lds16(A + (size_t)(m0 + (tid >> 2)) * K + k0 + (tid & 3) * 8,
               As + (size_t)(wave * 64) * 8);
    load_lds16(B + (size_t)(n0 + (tid >> 2)) * K + k0 + (tid & 3) * 8,
               Bs + (size_t)(wave * 64) * 8);
    __syncthreads();
    bf16x8 af[2], bfr[2];
#pragma unroll
    for (int i = 0; i < 2; ++i) af[i]  = ld_frag(As + (mw + i * 16 + l16) * 32 + quad * 8);
#pragma unroll
    for (int j = 0; j < 2; ++j) bfr[j] = ld_frag(Bs + (nw + j * 16 + l16) * 32 + quad * 8);
#pragma unroll
    for (int i = 0; i < 2; ++i)
#pragma unroll
      for (int j = 0; j < 2; ++j)
        acc[i][j] = __builtin_amdgcn_mfma_f32_16x16x32_bf16(af[i], bfr[j], acc[i][j], 0, 0, 0);
    __syncthreads();
  }
#pragma unroll
  for (int i = 0; i < 2; ++i)
#pragma unroll
    for (int j = 0; j < 2; ++j)
#pragma unroll
      for (int r = 0; r < 4; ++r) {
        int row = m0 + mw + i * 16 + quad * 4 + r;
        int col = n0 + nw + j * 16 + l16;
        C[(size_t)row * N + col] = acc[i][j][r];
      }
}

// ---------------------------------------------------------------------------
// Causal flash attention, K-SPLIT + pair-balanced: grid (32,12,2);
// x = pair*2 + j; block does q-tiles {p, 31-p}, K-tiles kt ≡ j (mod 2).
// Q pre-scaled by 1/8. K staged in LDS; V read DIRECT from padded Vt (L2).
// P packed to LDS by truncation. Emits unnormalized partials + (m,l).
// ---------------------------------------------------------------------------
__global__ __launch_bounds__(256) void attn_kernel(
    const ushort* __restrict__ Qb, const ushort* __restrict__ Kb,
    const ushort* __restrict__ Vt, ushort* __restrict__ Opart,
    float2* __restrict__ MLp)
{
  const int S = 2048, DM = 768;
  const int pair = blockIdx.x >> 1, j = blockIdx.x & 1;
  const int h = blockIdx.y, bb = blockIdx.z;
  const ushort* Qp  = Qb + (size_t)bb * S * DM + h * 64;
  const ushort* Kp  = Kb + (size_t)bb * S * DM + h * 64;
  const ushort* Vth = Vt + ((size_t)bb * 12 + h) * 64 * VS;   // [dv][s]

  __shared__ ushort Ks[128 * 72];     // [kk][dk], pad 64->72
  __shared__ ushort Ps[4][16 * 136];  // per-wave P[q][kk], pad 128->136

  const int tid = threadIdx.x, wave = tid >> 6, lane = tid & 63;
  const int quad = lane >> 4, l16 = lane & 15;
  const float LOG2E = 1.44269504f;
  const float NEG_BIG = -1.0e30f;

  for (int sp = 0; sp < 2; ++sp) {
    const int qt = sp == 0 ? pair : 31 - pair;
    const int q0 = qt * 64;
    const int qg = q0 + wave * 16 + l16;   // this lane's q row

    // Q fragments (B operand of S^T = K*Q^T)
    bf16x8 bq0 = ld_frag(Qp + (size_t)qg * DM + quad * 8);
    bf16x8 bq1 = ld_frag(Qp + (size_t)qg * DM + 32 + quad * 8);

    f32x4 acc_o[4] = {};
    float m_run = NEG_BIG, l_run = 0.0f;
    const int nkt = (qt >> 1) + 1;

    for (int kt = j; kt < nkt; kt += 2) {
      const int kk0 = kt * 128;
      // stage K tile: chunk c -> row c>>3, col (c&7)*8
#pragma unroll
      for (int i = 0; i < 4; ++i) {
        int c = i * 256 + tid;
        int r = c >> 3, col = (c & 7) * 8;
        *(u4a*)(Ks + r * 72 + col) = *(const u4a*)(Kp + (size_t)(kk0 + r) * DM + col);
      }
      __syncthreads();

      // S^T strip: this wave's 16 q cols x 128 kk rows = 8 tiles
      f32x4 sacc[8] = {};
#pragma unroll
      for (int tt = 0; tt < 8; ++tt) {
        bf16x8 ak0 = ld_frag(Ks + (tt * 16 + l16) * 72 + quad * 8);
        bf16x8 ak1 = ld_frag(Ks + (tt * 16 + l16) * 72 + 32 + quad * 8);
        sacc[tt] = __builtin_amdgcn_mfma_f32_16x16x32_bf16(ak0, bq0, sacc[tt], 0, 0, 0);
        sacc[tt] = __builtin_amdgcn_mfma_f32_16x16x32_bf16(ak1, bq1, sacc[tt], 0, 0, 0);
      }

      // causal mask (only the diagonal tile needs it); Q pre-scaled -> no mul
      const bool domask = (kt == nkt - 1);
      float mt = NEG_BIG;
#pragma unroll
      for (int tt = 0; tt < 8; ++tt)
#pragma unroll
        for (int r = 0; r < 4; ++r) {
          float s = sacc[tt][r];
          if (domask) {
            int kkg = kk0 + tt * 16 + quad * 4 + r;
            if (kkg > qg) s = NEG_BIG;
          }
          sacc[tt][r] = s;
          mt = fmaxf(mt, s);
        }
      mt = fmaxf(mt, __shfl_xor(mt, 16, 64));
      mt = fmaxf(mt, __shfl_xor(mt, 32, 64));
      float mnew = fmaxf(m_run, mt);
      float alpha = exp2f((m_run - mnew) * LOG2E);
      float lsum = 0.0f;
#pragma unroll
      for (int tt = 0; tt < 8; ++tt) {
        float p0 = exp2f((sacc[tt][0] - mnew) * LOG2E);
        float p1 = exp2f((sacc[tt][1] - mnew) * LOG2E);
        float p2 = exp2f((sacc[tt][2] - mnew) * LOG2E);
        float p3 = exp2f((sacc[tt][3] - mnew) * LOG2E);
        lsum += (p0 + p1) + (p2 + p3);
        // truncation pack (P in [0,1]: <=2^-8 rel err, well under threshold)
        uint32_t u0 = __builtin_bit_cast(uint32_t, p0);
        uint32_t u1 = __builtin_bit_cast(uint32_t, p1);
        uint32_t u2 = __builtin_bit_cast(uint32_t, p2);
        uint32_t u3 = __builtin_bit_cast(uint32_t, p3);
        u2a pw;
        pw.x = (u0 >> 16) | (u1 & 0xFFFF0000u);
        pw.y = (u2 >> 16) | (u3 & 0xFFFF0000u);
        *(u2a*)(&Ps[wave][l16 * 136 + tt * 16 + quad * 4]) = pw;
      }
      // Ps is per-wave: drain own LDS writes, forbid compile-time reordering.
      asm volatile("s_waitcnt lgkmcnt(0)" ::: "memory");
      lsum += __shfl_xor(lsum, 16, 64);
      lsum += __shfl_xor(lsum, 32, 64);
      l_run = l_run * alpha + lsum;
      m_run = mnew;

      // rescale O: O rows are q = quad*4+reg, alpha lives at lane l16==q
      float ar0 = __shfl(alpha, quad * 4 + 0, 64);
      float ar1 = __shfl(alpha, quad * 4 + 1, 64);
      float ar2 = __shfl(alpha, quad * 4 + 2, 64);
      float ar3 = __shfl(alpha, quad * 4 + 3, 64);
#pragma unroll
      for (int ct = 0; ct < 4; ++ct) {
        acc_o[ct][0] *= ar0; acc_o[ct][1] *= ar1;
        acc_o[ct][2] *= ar2; acc_o[ct][3] *= ar3;
      }

      // O += P*V : A=P from LDS, B=V fragments DIRECT from Vt (L2-resident)
      const ushort* vb = Vth + kk0;
#pragma unroll
      for (int ks = 0; ks < 4; ++ks) {
        bf16x8 ap = ld_frag(&Ps[wave][l16 * 136 + ks * 32 + quad * 8]);
#pragma unroll
        for (int ct = 0; ct < 4; ++ct) {
          bf16x8 bv = ld_frag(vb + (size_t)(ct * 16 + l16) * VS + ks * 32 + quad * 8);
          acc_o[ct] = __builtin_amdgcn_mfma_f32_16x16x32_bf16(ap, bv, acc_o[ct], 0, 0, 0);
        }
      }
      __syncthreads();   // protect Ks before next restage
    }

    // store unnormalized partial (bf16 O + per-row m,l)
    const int slot = (((bb * 12 + h) << 5) + qt) * 2 + j;
    ushort* Os = Opart + (size_t)slot * 4096;
    const int r0 = wave * 16 + quad * 4;
#pragma unroll
    for (int ct = 0; ct < 4; ++ct) {
      int col = ct * 16 + l16;
      Os[(r0 + 0) * 64 + col] = f2b(acc_o[ct][0]);
      Os[(r0 + 1) * 64 + col] = f2b(acc_o[ct][1]);
      Os[(r0 + 2) * 64 + col] = f2b(acc_o[ct][2]);
      Os[(r0 + 3) * 64 + col] = f2b(acc_o[ct][3]);
    }
    if (quad == 0)
      MLp[(size_t)slot * 64 + wave * 16 + l16] = make_float2(m_run, l_run);
  }
}

// ---------------------------------------------------------------------------
// Combine the two K-parity partials per strip -> Abuf (b, s, h*64) bf16.
// grid 768 (one block per strip), 256 threads, 16 elems/thread.
// ---------------------------------------------------------------------------
__global__ __launch_bounds__(256) void combine_kernel(
    const ushort* __restrict__ Opart, const float2* __restrict__ MLp,
    ushort* __restrict__ Ab)
{
  const int sid = blockIdx.x;
  const int bb = sid / 384, rem = sid % 384, h = rem >> 5, qt = rem & 31;
  const int t = threadIdx.x, row = t >> 2, cg = (t & 3) * 16;
  float2 ml0 = MLp[(size_t)(sid * 2) * 64 + row];
  float2 ml1 = MLp[(size_t)(sid * 2 + 1) * 64 + row];
  float ms = fmaxf(ml0.x, ml1.x);
  float w0 = exp2f((ml0.x - ms) * 1.44269504f);
  float w1 = exp2f((ml1.x - ms) * 1.44269504f);
  float inv = 1.0f / (ml0.y * w0 + ml1.y * w1);
  w0 *= inv; w1 *= inv;
  const ushort* p0 = Opart + (size_t)(sid * 2) * 4096 + row * 64 + cg;
  ushort* dst = Ab + ((size_t)(bb * 2048 + qt * 64 + row)) * 768 + h * 64 + cg;
#pragma unroll
  for (int g = 0; g < 2; ++g) {
    u4a a = *(const u4a*)(p0 + g * 8);
    u4a b = *(const u4a*)(p0 + 4096 + g * 8);
    u4a o;
    o.x = comb2(a.x, b.x, w0, w1);
    o.y = comb2(a.y, b.y, w0, w1);
    o.z = comb2(a.z, b.z, w0, w1);
    o.w = comb2(a.w, b.w, w0, w1);
    *(u4a*)(dst + g * 8) = o;
  }
}

// ---------------------------------------------------------------------------
extern "C" void kernel_launch(void* const* d_in, const int* in_sizes, int n_in,
                              void* d_out, int out_size, void* d_ws, size_t ws_size,
                              hipStream_t stream) {
  (void)in_sizes; (void)n_in; (void)out_size; (void)ws_size;
  const float* x  = (const float*)d_in[0];
  const float* wq = (const float*)d_in[1];
  const float* wk = (const float*)d_in[2];
  const float* wv = (const float*)d_in[3];
  const float* wo = (const float*)d_in[4];

  const size_t NT = (size_t)4096 * 768;   // tokens x d_model
  const size_t NW = (size_t)768 * 768;
  const size_t NV = (size_t)24 * 64 * VS; // padded Vt
  ushort* xb    = (ushort*)d_ws;          // reused as Abuf after QKV GEMM
  ushort* Qbuf  = xb + NT;
  ushort* Kbuf  = Qbuf + NT;
  ushort* Vt    = Kbuf + NT;              // (b, h, dv, s) stride VS
  ushort* wqb   = Vt + NV;
  ushort* wkb   = wqb + NW;
  ushort* wvb   = wkb + NW;
  ushort* wob   = wvb + NW;
  ushort* Opart = wob + NW;               // 1536 x 64 x 64 bf16
  float2* MLp   = (float2*)(Opart + (size_t)1536 * 4096);  // 1536 x 64
  ushort* Abuf  = xb;                     // lifetime-disjoint reuse

  // fp32 -> bf16 (x + all weights)
  convert_kernel<<<2688, 256, 0, stream>>>(x, wq, wk, wv, wo,
                                           xb, wqb, wkb, wvb, wob);
  // Q/K/V projections (Q pre-scaled; V lands transposed in Vt)
  gemm_qkv<<<dim3(32, 12, 3), 256, 0, stream>>>(
      xb, wqb, wkb, wvb, Qbuf, Kbuf, Vt, 4096, 768, 768);
  // causal flash attention: 768 uniform K-split sub-blocks -> partials
  attn_kernel<<<dim3(32, 12, 2), 256, 0, stream>>>(Qbuf, Kbuf, Vt, Opart, MLp);
  // merge partials -> Abuf
  combine_kernel<<<768, 256, 0, stream>>>(Opart, MLp, Abuf);
  // output projection (fp32 out)
  gemm_out<<<dim3(64, 12), 256, 0, stream>>>(
      Abuf, wob, (float*)d_out, 4096, 768, 768);
}

// Round 9
// 174.379 us; speedup vs baseline: 1.1436x; 1.1436x over previous
//
#include <hip/hip_runtime.h>
#include <stdint.h>

typedef float f32x4 __attribute__((ext_vector_type(4)));
typedef __bf16 bf16x8 __attribute__((ext_vector_type(8)));
typedef uint32_t u32a  __attribute__((may_alias));
typedef uint2    u2a   __attribute__((may_alias));
typedef uint4    u4a   __attribute__((may_alias));

#define VS 2064   // Vt row stride in elements (2048 + 16: breaks 4KB L2 aliasing)

__device__ __forceinline__ ushort f2b(float f) {
  uint32_t u = __builtin_bit_cast(uint32_t, f);
  u += 0x7FFFu + ((u >> 16) & 1u);   // round-to-nearest-even
  return (ushort)(u >> 16);
}
__device__ __forceinline__ uint32_t b16(uint32_t u) {  // fp32 bits -> bf16 bits (RNE)
  u += 0x7FFFu + ((u >> 16) & 1u);
  return u >> 16;
}

__device__ __forceinline__ bf16x8 ld_frag(const ushort* p) {
  u4a u = *(const u4a*)p;            // ds_read_b128 / global_load_dwordx4
  return __builtin_bit_cast(bf16x8, u);
}

// 8 fp32 -> 8 bf16 packed (two dwordx4 loads + RNE pack)
__device__ __forceinline__ u4a cvt8(const float* p) {
  u4a a = *(const u4a*)p, b = *(const u4a*)(p + 4), o;
  o.x = b16(a.x) | (b16(a.y) << 16);
  o.y = b16(a.z) | (b16(a.w) << 16);
  o.z = b16(b.x) | (b16(b.y) << 16);
  o.w = b16(b.z) | (b16(b.w) << 16);
  return o;
}

__device__ __forceinline__ void load_lds16(const void* g, void* l) {
  __builtin_amdgcn_global_load_lds(
      (const __attribute__((address_space(1))) uint32_t*)g,
      (__attribute__((address_space(3))) uint32_t*)l, 16, 0, 0);
}

// combine two packed bf16 pairs with weights w0,w1, repack
__device__ __forceinline__ uint32_t comb2(uint32_t a, uint32_t b, float w0, float w1) {
  float lo = __builtin_bit_cast(float, a << 16) * w0 +
             __builtin_bit_cast(float, b << 16) * w1;
  float hi = __builtin_bit_cast(float, a & 0xFFFF0000u) * w0 +
             __builtin_bit_cast(float, b & 0xFFFF0000u) * w1;
  return (uint32_t)f2b(lo) | ((uint32_t)f2b(hi) << 16);
}

// ---------------------------------------------------------------------------
// fp32 -> bf16 one-shot convert: x (3145728) then wq/wk/wv/wo (589824 each).
// ---------------------------------------------------------------------------
__global__ __launch_bounds__(256) void convert_kernel(
    const float* __restrict__ x,  const float* __restrict__ wq,
    const float* __restrict__ wk, const float* __restrict__ wv,
    const float* __restrict__ wo,
    ushort* __restrict__ xb,  ushort* __restrict__ wqb,
    ushort* __restrict__ wkb, ushort* __restrict__ wvb,
    ushort* __restrict__ wob)
{
  const size_t NX = 3145728, NW = 589824;
  size_t idx = ((size_t)blockIdx.x * 256 + threadIdx.x) * 8;
  const float* src; ushort* dst; size_t off;
  if      (idx < NX)          { src = x;  dst = xb;  off = idx; }
  else if (idx < NX + NW)     { src = wq; dst = wqb; off = idx - NX; }
  else if (idx < NX + 2 * NW) { src = wk; dst = wkb; off = idx - NX - NW; }
  else if (idx < NX + 3 * NW) { src = wv; dst = wvb; off = idx - NX - 2 * NW; }
  else                        { src = wo; dst = wob; off = idx - NX - 3 * NW; }
  *(u4a*)(dst + off) = cvt8(src + off);
}

// ---------------------------------------------------------------------------
// QKV: C[M,N]=A[M,K]*B[N,K]^T, bf16, fp32 acc. BM=128 BN=64 BK=32, 256 thr.
// grid (32, 12, 3): y-tile == one head. z: 0->Q (PRE-SCALED by 1/8),
// 1->K row-major; 2->V written transposed to Vt[b][h][dv][s] (stride VS).
// ---------------------------------------------------------------------------
__global__ __launch_bounds__(256) void gemm_qkv(
    const ushort* __restrict__ A,
    const ushort* __restrict__ B0, const ushort* __restrict__ B1,
    const ushort* __restrict__ B2,
    ushort* __restrict__ Qo, ushort* __restrict__ Ko, ushort* __restrict__ Vt,
    int M, int N, int K)
{
  const ushort* B = blockIdx.z == 0 ? B0 : (blockIdx.z == 1 ? B1 : B2);
  const int m0 = blockIdx.x * 128, n0 = blockIdx.y * 64;
  __shared__ ushort As[128 * 32];   // linear chunk order (global_load_lds layout)
  __shared__ ushort Bs[64 * 32];
  const int tid = threadIdx.x, wave = tid >> 6, lane = tid & 63;
  const int quad = lane >> 4, l16 = lane & 15;
  const int mw = (wave & 1) * 64, nw = (wave >> 1) * 32;
  f32x4 acc[4][2] = {};

  for (int k0 = 0; k0 < K; k0 += 32) {
    // A: 512 chunks of 16B (2/thread); B: 256 chunks (1/thread)
#pragma unroll
    for (int i = 0; i < 2; ++i) {
      int c = i * 256 + tid;
      load_lds16(A + (size_t)(m0 + (c >> 2)) * K + k0 + (c & 3) * 8,
                 As + (size_t)(i * 256 + wave * 64) * 8);
    }
    load_lds16(B + (size_t)(n0 + (tid >> 2)) * K + k0 + (tid & 3) * 8,
               Bs + (size_t)(wave * 64) * 8);
    __syncthreads();
    bf16x8 af[4], bfr[2];
#pragma unroll
    for (int i = 0; i < 4; ++i) af[i]  = ld_frag(As + (mw + i * 16 + l16) * 32 + quad * 8);
#pragma unroll
    for (int j = 0; j < 2; ++j) bfr[j] = ld_frag(Bs + (nw + j * 16 + l16) * 32 + quad * 8);
#pragma unroll
    for (int i = 0; i < 4; ++i)
#pragma unroll
      for (int j = 0; j < 2; ++j)
        acc[i][j] = __builtin_amdgcn_mfma_f32_16x16x32_bf16(af[i], bfr[j], acc[i][j], 0, 0, 0);
    __syncthreads();
  }
  // C/D layout: col=lane&15 (N), row=quad*4+reg (M)
  if (blockIdx.z < 2) {
    ushort* C = blockIdx.z == 0 ? Qo : Ko;
    const float sc = blockIdx.z == 0 ? 0.125f : 1.0f;  // fold 1/sqrt(dk) into Q
#pragma unroll
    for (int i = 0; i < 4; ++i)
#pragma unroll
      for (int j = 0; j < 2; ++j)
#pragma unroll
        for (int r = 0; r < 4; ++r) {
          int row = m0 + mw + i * 16 + quad * 4 + r;
          int col = n0 + nw + j * 16 + l16;
          C[(size_t)row * N + col] = f2b(acc[i][j][r] * sc);
        }
  } else {
    // Vt[b][h][dv][s] (stride VS): h == blockIdx.y, dv = col&63
#pragma unroll
    for (int i = 0; i < 4; ++i)
#pragma unroll
      for (int j = 0; j < 2; ++j) {
        int col = n0 + nw + j * 16 + l16;
        int h = col >> 6, dv = col & 63;
        int t = m0 + mw + i * 16 + quad * 4;
        int b = t >> 11, s = t & 2047;
        u2a pw;
        pw.x = (uint32_t)f2b(acc[i][j][0]) | ((uint32_t)f2b(acc[i][j][1]) << 16);
        pw.y = (uint32_t)f2b(acc[i][j][2]) | ((uint32_t)f2b(acc[i][j][3]) << 16);
        *(u2a*)(Vt + (((size_t)b * 12 + h) * 64 + dv) * VS + s) = pw;
      }
  }
}

// ---------------------------------------------------------------------------
// Output projection: C[M,N](fp32) = A[M,K](bf16)*B[N,K]^T(bf16).
// BM=BN=64, BK=32, 256 thr, grid (64,12) = 768 blocks (3/CU).
// ---------------------------------------------------------------------------
__global__ __launch_bounds__(256) void gemm_out(
    const ushort* __restrict__ A, const ushort* __restrict__ B,
    float* __restrict__ C, int M, int N, int K)
{
  const int m0 = blockIdx.x * 64, n0 = blockIdx.y * 64;
  __shared__ ushort As[64 * 32];
  __shared__ ushort Bs[64 * 32];
  const int tid = threadIdx.x, wave = tid >> 6, lane = tid & 63;
  const int quad = lane >> 4, l16 = lane & 15;
  const int mw = (wave & 1) * 32, nw = (wave >> 1) * 32;
  f32x4 acc[2][2] = {};

  for (int k0 = 0; k0 < K; k0 += 32) {
    load_lds16(A + (size_t)(m0 + (tid >> 2)) * K + k0 + (tid & 3) * 8,
               As + (size_t)(wave * 64) * 8);
    load_lds16(B + (size_t)(n0 + (tid >> 2)) * K + k0 + (tid & 3) * 8,
               Bs + (size_t)(wave * 64) * 8);
    __syncthreads();
    bf16x8 af[2], bfr[2];
#pragma unroll
    for (int i = 0; i < 2; ++i) af[i]  = ld_frag(As + (mw + i * 16 + l16) * 32 + quad * 8);
#pragma unroll
    for (int j = 0; j < 2; ++j) bfr[j] = ld_frag(Bs + (nw + j * 16 + l16) * 32 + quad * 8);
#pragma unroll
    for (int i = 0; i < 2; ++i)
#pragma unroll
      for (int j = 0; j < 2; ++j)
        acc[i][j] = __builtin_amdgcn_mfma_f32_16x16x32_bf16(af[i], bfr[j], acc[i][j], 0, 0, 0);
    __syncthreads();
  }
#pragma unroll
  for (int i = 0; i < 2; ++i)
#pragma unroll
    for (int j = 0; j < 2; ++j)
#pragma unroll
      for (int r = 0; r < 4; ++r) {
        int row = m0 + mw + i * 16 + quad * 4 + r;
        int col = n0 + nw + j * 16 + l16;
        C[(size_t)row * N + col] = acc[i][j][r];
      }
}

// ---------------------------------------------------------------------------
// Causal flash attention, K-SPLIT + pair-balanced: grid (32,12,2);
// x = pair*2 + j; block does q-tiles {p, 31-p}, K-tiles kt ≡ j (mod 2).
// Q pre-scaled by 1/8. K and V staged in LDS (V via padded Vt, b128 copies).
// P packed to LDS by truncation. Emits unnormalized partials + (m,l).
// ---------------------------------------------------------------------------
__global__ __launch_bounds__(256) void attn_kernel(
    const ushort* __restrict__ Qb, const ushort* __restrict__ Kb,
    const ushort* __restrict__ Vt, ushort* __restrict__ Opart,
    float2* __restrict__ MLp)
{
  const int S = 2048, DM = 768;
  const int pair = blockIdx.x >> 1, j = blockIdx.x & 1;
  const int h = blockIdx.y, bb = blockIdx.z;
  const ushort* Qp  = Qb + (size_t)bb * S * DM + h * 64;
  const ushort* Kp  = Kb + (size_t)bb * S * DM + h * 64;
  const ushort* Vth = Vt + ((size_t)bb * 12 + h) * 64 * VS;   // [dv][s]

  __shared__ ushort Ks[128 * 72];     // [kk][dk], pad 64->72
  __shared__ ushort Vs[64 * 136];     // [dv][kk], pad 128->136
  __shared__ ushort Ps[4][16 * 136];  // per-wave P[q][kk], pad 128->136

  const int tid = threadIdx.x, wave = tid >> 6, lane = tid & 63;
  const int quad = lane >> 4, l16 = lane & 15;
  const float LOG2E = 1.44269504f;
  const float NEG_BIG = -1.0e30f;

  for (int sp = 0; sp < 2; ++sp) {
    const int qt = sp == 0 ? pair : 31 - pair;
    const int q0 = qt * 64;
    const int qg = q0 + wave * 16 + l16;   // this lane's q row

    // Q fragments (B operand of S^T = K*Q^T)
    bf16x8 bq0 = ld_frag(Qp + (size_t)qg * DM + quad * 8);
    bf16x8 bq1 = ld_frag(Qp + (size_t)qg * DM + 32 + quad * 8);

    f32x4 acc_o[4] = {};
    float m_run = NEG_BIG, l_run = 0.0f;
    const int nkt = (qt >> 1) + 1;

    for (int kt = j; kt < nkt; kt += 2) {
      const int kk0 = kt * 128;
      // stage K tile: chunk c -> row c>>3, col (c&7)*8
#pragma unroll
      for (int i = 0; i < 4; ++i) {
        int c = i * 256 + tid;
        int r = c >> 3, col = (c & 7) * 8;
        *(u4a*)(Ks + r * 72 + col) = *(const u4a*)(Kp + (size_t)(kk0 + r) * DM + col);
      }
      // stage V tile from Vt: chunk c -> dv c>>4, kk (c&15)*8
#pragma unroll
      for (int i = 0; i < 4; ++i) {
        int c = i * 256 + tid;
        int dv = c >> 4, kc = (c & 15) * 8;
        *(u4a*)(Vs + dv * 136 + kc) = *(const u4a*)(Vth + (size_t)dv * VS + kk0 + kc);
      }
      __syncthreads();

      // S^T strip: this wave's 16 q cols x 128 kk rows = 8 tiles
      f32x4 sacc[8] = {};
#pragma unroll
      for (int tt = 0; tt < 8; ++tt) {
        bf16x8 ak0 = ld_frag(Ks + (tt * 16 + l16) * 72 + quad * 8);
        bf16x8 ak1 = ld_frag(Ks + (tt * 16 + l16) * 72 + 32 + quad * 8);
        sacc[tt] = __builtin_amdgcn_mfma_f32_16x16x32_bf16(ak0, bq0, sacc[tt], 0, 0, 0);
        sacc[tt] = __builtin_amdgcn_mfma_f32_16x16x32_bf16(ak1, bq1, sacc[tt], 0, 0, 0);
      }

      // causal mask (only the diagonal tile needs it); Q pre-scaled -> no mul
      const bool domask = (kt == nkt - 1);
      float mt = NEG_BIG;
#pragma unroll
      for (int tt = 0; tt < 8; ++tt)
#pragma unroll
        for (int r = 0; r < 4; ++r) {
          float s = sacc[tt][r];
          if (domask) {
            int kkg = kk0 + tt * 16 + quad * 4 + r;
            if (kkg > qg) s = NEG_BIG;
          }
          sacc[tt][r] = s;
          mt = fmaxf(mt, s);
        }
      mt = fmaxf(mt, __shfl_xor(mt, 16, 64));
      mt = fmaxf(mt, __shfl_xor(mt, 32, 64));
      float mnew = fmaxf(m_run, mt);
      float alpha = exp2f((m_run - mnew) * LOG2E);
      float lsum = 0.0f;
#pragma unroll
      for (int tt = 0; tt < 8; ++tt) {
        float p0 = exp2f((sacc[tt][0] - mnew) * LOG2E);
        float p1 = exp2f((sacc[tt][1] - mnew) * LOG2E);
        float p2 = exp2f((sacc[tt][2] - mnew) * LOG2E);
        float p3 = exp2f((sacc[tt][3] - mnew) * LOG2E);
        lsum += (p0 + p1) + (p2 + p3);
        // truncation pack (P in [0,1]: <=2^-8 rel err, well under threshold)
        uint32_t u0 = __builtin_bit_cast(uint32_t, p0);
        uint32_t u1 = __builtin_bit_cast(uint32_t, p1);
        uint32_t u2 = __builtin_bit_cast(uint32_t, p2);
        uint32_t u3 = __builtin_bit_cast(uint32_t, p3);
        u2a pw;
        pw.x = (u0 >> 16) | (u1 & 0xFFFF0000u);
        pw.y = (u2 >> 16) | (u3 & 0xFFFF0000u);
        *(u2a*)(&Ps[wave][l16 * 136 + tt * 16 + quad * 4]) = pw;
      }
      // Ps is per-wave: drain own LDS writes, forbid compile-time reordering.
      asm volatile("s_waitcnt lgkmcnt(0)" ::: "memory");
      lsum += __shfl_xor(lsum, 16, 64);
      lsum += __shfl_xor(lsum, 32, 64);
      l_run = l_run * alpha + lsum;
      m_run = mnew;

      // rescale O: O rows are q = quad*4+reg, alpha lives at lane l16==q
      float ar0 = __shfl(alpha, quad * 4 + 0, 64);
      float ar1 = __shfl(alpha, quad * 4 + 1, 64);
      float ar2 = __shfl(alpha, quad * 4 + 2, 64);
      float ar3 = __shfl(alpha, quad * 4 + 3, 64);
#pragma unroll
      for (int ct = 0; ct < 4; ++ct) {
        acc_o[ct][0] *= ar0; acc_o[ct][1] *= ar1;
        acc_o[ct][2] *= ar2; acc_o[ct][3] *= ar3;
      }

      // O += P*V : A=P from LDS, B=V via Vs[dv][kk]
#pragma unroll
      for (int ks = 0; ks < 4; ++ks) {
        bf16x8 ap = ld_frag(&Ps[wave][l16 * 136 + ks * 32 + quad * 8]);
#pragma unroll
        for (int ct = 0; ct < 4; ++ct) {
          bf16x8 bv = ld_frag(Vs + (size_t)(ct * 16 + l16) * 136 + ks * 32 + quad * 8);
          acc_o[ct] = __builtin_amdgcn_mfma_f32_16x16x32_bf16(ap, bv, acc_o[ct], 0, 0, 0);
        }
      }
      __syncthreads();   // protect Ks/Vs before next restage
    }

    // store unnormalized partial (bf16 O + per-row m,l)
    const int slot = (((bb * 12 + h) << 5) + qt) * 2 + j;
    ushort* Os = Opart + (size_t)slot * 4096;
    const int r0 = wave * 16 + quad * 4;
#pragma unroll
    for (int ct = 0; ct < 4; ++ct) {
      int col = ct * 16 + l16;
      Os[(r0 + 0) * 64 + col] = f2b(acc_o[ct][0]);
      Os[(r0 + 1) * 64 + col] = f2b(acc_o[ct][1]);
      Os[(r0 + 2) * 64 + col] = f2b(acc_o[ct][2]);
      Os[(r0 + 3) * 64 + col] = f2b(acc_o[ct][3]);
    }
    if (quad == 0)
      MLp[(size_t)slot * 64 + wave * 16 + l16] = make_float2(m_run, l_run);
  }
}

// ---------------------------------------------------------------------------
// Combine the two K-parity partials per strip -> Abuf (b, s, h*64) bf16.
// grid 768 (one block per strip), 256 threads, 16 elems/thread.
// ---------------------------------------------------------------------------
__global__ __launch_bounds__(256) void combine_kernel(
    const ushort* __restrict__ Opart, const float2* __restrict__ MLp,
    ushort* __restrict__ Ab)
{
  const int sid = blockIdx.x;
  const int bb = sid / 384, rem = sid % 384, h = rem >> 5, qt = rem & 31;
  const int t = threadIdx.x, row = t >> 2, cg = (t & 3) * 16;
  float2 ml0 = MLp[(size_t)(sid * 2) * 64 + row];
  float2 ml1 = MLp[(size_t)(sid * 2 + 1) * 64 + row];
  float ms = fmaxf(ml0.x, ml1.x);
  float w0 = exp2f((ml0.x - ms) * 1.44269504f);
  float w1 = exp2f((ml1.x - ms) * 1.44269504f);
  float inv = 1.0f / (ml0.y * w0 + ml1.y * w1);
  w0 *= inv; w1 *= inv;
  const ushort* p0 = Opart + (size_t)(sid * 2) * 4096 + row * 64 + cg;
  ushort* dst = Ab + ((size_t)(bb * 2048 + qt * 64 + row)) * 768 + h * 64 + cg;
#pragma unroll
  for (int g = 0; g < 2; ++g) {
    u4a a = *(const u4a*)(p0 + g * 8);
    u4a b = *(const u4a*)(p0 + 4096 + g * 8);
    u4a o;
    o.x = comb2(a.x, b.x, w0, w1);
    o.y = comb2(a.y, b.y, w0, w1);
    o.z = comb2(a.z, b.z, w0, w1);
    o.w = comb2(a.w, b.w, w0, w1);
    *(u4a*)(dst + g * 8) = o;
  }
}

// ---------------------------------------------------------------------------
extern "C" void kernel_launch(void* const* d_in, const int* in_sizes, int n_in,
                              void* d_out, int out_size, void* d_ws, size_t ws_size,
                              hipStream_t stream) {
  (void)in_sizes; (void)n_in; (void)out_size; (void)ws_size;
  const float* x  = (const float*)d_in[0];
  const float* wq = (const float*)d_in[1];
  const float* wk = (const float*)d_in[2];
  const float* wv = (const float*)d_in[3];
  const float* wo = (const float*)d_in[4];

  const size_t NT = (size_t)4096 * 768;   // tokens x d_model
  const size_t NW = (size_t)768 * 768;
  const size_t NV = (size_t)24 * 64 * VS; // padded Vt
  ushort* xb    = (ushort*)d_ws;          // reused as Abuf after QKV GEMM
  ushort* Qbuf  = xb + NT;
  ushort* Kbuf  = Qbuf + NT;
  ushort* Vt    = Kbuf + NT;              // (b, h, dv, s) stride VS
  ushort* wqb   = Vt + NV;
  ushort* wkb   = wqb + NW;
  ushort* wvb   = wkb + NW;
  ushort* wob   = wvb + NW;
  ushort* Opart = wob + NW;               // 1536 x 64 x 64 bf16
  float2* MLp   = (float2*)(Opart + (size_t)1536 * 4096);  // 1536 x 64
  ushort* Abuf  = xb;                     // lifetime-disjoint reuse

  // fp32 -> bf16 (x + all weights)
  convert_kernel<<<2688, 256, 0, stream>>>(x, wq, wk, wv, wo,
                                           xb, wqb, wkb, wvb, wob);
  // Q/K/V projections (Q pre-scaled; V lands transposed in Vt)
  gemm_qkv<<<dim3(32, 12, 3), 256, 0, stream>>>(
      xb, wqb, wkb, wvb, Qbuf, Kbuf, Vt, 4096, 768, 768);
  // causal flash attention: 768 uniform K-split sub-blocks -> partials
  attn_kernel<<<dim3(32, 12, 2), 256, 0, stream>>>(Qbuf, Kbuf, Vt, Opart, MLp);
  // merge partials -> Abuf
  combine_kernel<<<768, 256, 0, stream>>>(Opart, MLp, Abuf);
  // output projection (fp32 out)
  gemm_out<<<dim3(64, 12), 256, 0, stream>>>(
      Abuf, wob, (float*)d_out, 4096, 768, 768);
}

// Round 10
// 173.008 us; speedup vs baseline: 1.1526x; 1.0079x over previous
//
#include <hip/hip_runtime.h>
#include <stdint.h>

typedef float f32x4 __attribute__((ext_vector_type(4)));
typedef __bf16 bf16x8 __attribute__((ext_vector_type(8)));
typedef uint32_t u32a  __attribute__((may_alias));
typedef uint2    u2a   __attribute__((may_alias));
typedef uint4    u4a   __attribute__((may_alias));

#define VS 2064   // Vt row stride in elements (2048 + 16: breaks 4KB L2 aliasing)

__device__ __forceinline__ ushort f2b(float f) {
  uint32_t u = __builtin_bit_cast(uint32_t, f);
  u += 0x7FFFu + ((u >> 16) & 1u);   // round-to-nearest-even
  return (ushort)(u >> 16);
}
__device__ __forceinline__ uint32_t b16(uint32_t u) {  // fp32 bits -> bf16 bits (RNE)
  u += 0x7FFFu + ((u >> 16) & 1u);
  return u >> 16;
}

__device__ __forceinline__ bf16x8 ld_frag(const ushort* p) {
  u4a u = *(const u4a*)p;            // ds_read_b128 / global_load_dwordx4
  return __builtin_bit_cast(bf16x8, u);
}

// 8 fp32 -> 8 bf16 packed (two dwordx4 loads + RNE pack)
__device__ __forceinline__ u4a cvt8(const float* p) {
  u4a a = *(const u4a*)p, b = *(const u4a*)(p + 4), o;
  o.x = b16(a.x) | (b16(a.y) << 16);
  o.y = b16(a.z) | (b16(a.w) << 16);
  o.z = b16(b.x) | (b16(b.y) << 16);
  o.w = b16(b.z) | (b16(b.w) << 16);
  return o;
}

__device__ __forceinline__ void load_lds16(const void* g, void* l) {
  __builtin_amdgcn_global_load_lds(
      (const __attribute__((address_space(1))) uint32_t*)g,
      (__attribute__((address_space(3))) uint32_t*)l, 16, 0, 0);
}

// combine two packed bf16 pairs with weights w0,w1, repack
__device__ __forceinline__ uint32_t comb2(uint32_t a, uint32_t b, float w0, float w1) {
  float lo = __builtin_bit_cast(float, a << 16) * w0 +
             __builtin_bit_cast(float, b << 16) * w1;
  float hi = __builtin_bit_cast(float, a & 0xFFFF0000u) * w0 +
             __builtin_bit_cast(float, b & 0xFFFF0000u) * w1;
  return (uint32_t)f2b(lo) | ((uint32_t)f2b(hi) << 16);
}

// ---------------------------------------------------------------------------
// fp32 -> bf16 one-shot convert: x (3145728) then wq/wk/wv/wo (589824 each).
// ---------------------------------------------------------------------------
__global__ __launch_bounds__(256) void convert_kernel(
    const float* __restrict__ x,  const float* __restrict__ wq,
    const float* __restrict__ wk, const float* __restrict__ wv,
    const float* __restrict__ wo,
    ushort* __restrict__ xb,  ushort* __restrict__ wqb,
    ushort* __restrict__ wkb, ushort* __restrict__ wvb,
    ushort* __restrict__ wob)
{
  const size_t NX = 3145728, NW = 589824;
  size_t idx = ((size_t)blockIdx.x * 256 + threadIdx.x) * 8;
  const float* src; ushort* dst; size_t off;
  if      (idx < NX)          { src = x;  dst = xb;  off = idx; }
  else if (idx < NX + NW)     { src = wq; dst = wqb; off = idx - NX; }
  else if (idx < NX + 2 * NW) { src = wk; dst = wkb; off = idx - NX - NW; }
  else if (idx < NX + 3 * NW) { src = wv; dst = wvb; off = idx - NX - 2 * NW; }
  else                        { src = wo; dst = wob; off = idx - NX - 3 * NW; }
  *(u4a*)(dst + off) = cvt8(src + off);
}

// ---------------------------------------------------------------------------
// QKV: C[M,N]=A[M,K]*B[N,K]^T, bf16, fp32 acc. BM=128 BN=64 BK=64, 256 thr.
// grid (32, 12, 3): y-tile == one head. z: 0->Q (PRE-SCALED by 1/8),
// 1->K row-major; 2->V written transposed to Vt[b][h][dv][s] (stride VS).
// ---------------------------------------------------------------------------
__global__ __launch_bounds__(256) void gemm_qkv(
    const ushort* __restrict__ A,
    const ushort* __restrict__ B0, const ushort* __restrict__ B1,
    const ushort* __restrict__ B2,
    ushort* __restrict__ Qo, ushort* __restrict__ Ko, ushort* __restrict__ Vt,
    int M, int N, int K)
{
  const ushort* B = blockIdx.z == 0 ? B0 : (blockIdx.z == 1 ? B1 : B2);
  const int m0 = blockIdx.x * 128, n0 = blockIdx.y * 64;
  __shared__ ushort As[128 * 64];   // 16KB, linear chunk order (8 chunks/row)
  __shared__ ushort Bs[64 * 64];    // 8KB
  const int tid = threadIdx.x, wave = tid >> 6, lane = tid & 63;
  const int quad = lane >> 4, l16 = lane & 15;
  const int mw = (wave & 1) * 64, nw = (wave >> 1) * 32;
  f32x4 acc[4][2] = {};

  for (int k0 = 0; k0 < K; k0 += 64) {
    // A: 1024 chunks of 16B (4/thread); chunk c -> row c>>3, col (c&7)*8
#pragma unroll
    for (int i = 0; i < 4; ++i) {
      int c = i * 256 + tid;
      load_lds16(A + (size_t)(m0 + (c >> 3)) * K + k0 + (c & 7) * 8,
                 As + (size_t)(i * 256 + wave * 64) * 8);
    }
    // B: 512 chunks (2/thread)
#pragma unroll
    for (int i = 0; i < 2; ++i) {
      int c = i * 256 + tid;
      load_lds16(B + (size_t)(n0 + (c >> 3)) * K + k0 + (c & 7) * 8,
                 Bs + (size_t)(i * 256 + wave * 64) * 8);
    }
    __syncthreads();
#pragma unroll
    for (int ks = 0; ks < 2; ++ks) {
      bf16x8 af[4], bfr[2];
#pragma unroll
      for (int i = 0; i < 4; ++i)
        af[i]  = ld_frag(As + (mw + i * 16 + l16) * 64 + ks * 32 + quad * 8);
#pragma unroll
      for (int j = 0; j < 2; ++j)
        bfr[j] = ld_frag(Bs + (nw + j * 16 + l16) * 64 + ks * 32 + quad * 8);
#pragma unroll
      for (int i = 0; i < 4; ++i)
#pragma unroll
        for (int j = 0; j < 2; ++j)
          acc[i][j] = __builtin_amdgcn_mfma_f32_16x16x32_bf16(af[i], bfr[j], acc[i][j], 0, 0, 0);
    }
    __syncthreads();
  }
  // C/D layout: col=lane&15 (N), row=quad*4+reg (M)
  if (blockIdx.z < 2) {
    ushort* C = blockIdx.z == 0 ? Qo : Ko;
    const float sc = blockIdx.z == 0 ? 0.125f : 1.0f;  // fold 1/sqrt(dk) into Q
#pragma unroll
    for (int i = 0; i < 4; ++i)
#pragma unroll
      for (int j = 0; j < 2; ++j)
#pragma unroll
        for (int r = 0; r < 4; ++r) {
          int row = m0 + mw + i * 16 + quad * 4 + r;
          int col = n0 + nw + j * 16 + l16;
          C[(size_t)row * N + col] = f2b(acc[i][j][r] * sc);
        }
  } else {
    // Vt[b][h][dv][s] (stride VS): h == blockIdx.y, dv = col&63
#pragma unroll
    for (int i = 0; i < 4; ++i)
#pragma unroll
      for (int j = 0; j < 2; ++j) {
        int col = n0 + nw + j * 16 + l16;
        int h = col >> 6, dv = col & 63;
        int t = m0 + mw + i * 16 + quad * 4;
        int b = t >> 11, s = t & 2047;
        u2a pw;
        pw.x = (uint32_t)f2b(acc[i][j][0]) | ((uint32_t)f2b(acc[i][j][1]) << 16);
        pw.y = (uint32_t)f2b(acc[i][j][2]) | ((uint32_t)f2b(acc[i][j][3]) << 16);
        *(u2a*)(Vt + (((size_t)b * 12 + h) * 64 + dv) * VS + s) = pw;
      }
  }
}

// ---------------------------------------------------------------------------
// Output projection: C[M,N](fp32) = A[M,K](bf16)*B[N,K]^T(bf16).
// BM=BN=64, BK=64, 256 thr, grid (64,12) = 768 blocks (3/CU).
// ---------------------------------------------------------------------------
__global__ __launch_bounds__(256) void gemm_out(
    const ushort* __restrict__ A, const ushort* __restrict__ B,
    float* __restrict__ C, int M, int N, int K)
{
  const int m0 = blockIdx.x * 64, n0 = blockIdx.y * 64;
  __shared__ ushort As[64 * 64];
  __shared__ ushort Bs[64 * 64];
  const int tid = threadIdx.x, wave = tid >> 6, lane = tid & 63;
  const int quad = lane >> 4, l16 = lane & 15;
  const int mw = (wave & 1) * 32, nw = (wave >> 1) * 32;
  f32x4 acc[2][2] = {};

  for (int k0 = 0; k0 < K; k0 += 64) {
#pragma unroll
    for (int i = 0; i < 2; ++i) {
      int c = i * 256 + tid;
      load_lds16(A + (size_t)(m0 + (c >> 3)) * K + k0 + (c & 7) * 8,
                 As + (size_t)(i * 256 + wave * 64) * 8);
      load_lds16(B + (size_t)(n0 + (c >> 3)) * K + k0 + (c & 7) * 8,
                 Bs + (size_t)(i * 256 + wave * 64) * 8);
    }
    __syncthreads();
#pragma unroll
    for (int ks = 0; ks < 2; ++ks) {
      bf16x8 af[2], bfr[2];
#pragma unroll
      for (int i = 0; i < 2; ++i)
        af[i]  = ld_frag(As + (mw + i * 16 + l16) * 64 + ks * 32 + quad * 8);
#pragma unroll
      for (int j = 0; j < 2; ++j)
        bfr[j] = ld_frag(Bs + (nw + j * 16 + l16) * 64 + ks * 32 + quad * 8);
#pragma unroll
      for (int i = 0; i < 2; ++i)
#pragma unroll
        for (int j = 0; j < 2; ++j)
          acc[i][j] = __builtin_amdgcn_mfma_f32_16x16x32_bf16(af[i], bfr[j], acc[i][j], 0, 0, 0);
    }
    __syncthreads();
  }
#pragma unroll
  for (int i = 0; i < 2; ++i)
#pragma unroll
    for (int j = 0; j < 2; ++j)
#pragma unroll
      for (int r = 0; r < 4; ++r) {
        int row = m0 + mw + i * 16 + quad * 4 + r;
        int col = n0 + nw + j * 16 + l16;
        C[(size_t)row * N + col] = acc[i][j][r];
      }
}

// ---------------------------------------------------------------------------
// Causal flash attention, TILE-SHARED strips + K-split: grid (32,12,2);
// x = pair*2 + j. Block owns q-tiles A=pair, B=31-pair; iterates kt ≡ j (mod 2)
// up to nktB, staging each K/V tile ONCE and computing both strips from it
// (strip A only while kt < nktA). 768 blocks, uniform 17 compute-units each.
// Q pre-scaled by 1/8. Emits unnormalized partials + (m,l) per strip.
// ---------------------------------------------------------------------------
__global__ __launch_bounds__(256) void attn_kernel(
    const ushort* __restrict__ Qb, const ushort* __restrict__ Kb,
    const ushort* __restrict__ Vt, ushort* __restrict__ Opart,
    float2* __restrict__ MLp)
{
  const int S = 2048, DM = 768;
  const int pair = blockIdx.x >> 1, j = blockIdx.x & 1;
  const int h = blockIdx.y, bb = blockIdx.z;
  const ushort* Qp  = Qb + (size_t)bb * S * DM + h * 64;
  const ushort* Kp  = Kb + (size_t)bb * S * DM + h * 64;
  const ushort* Vth = Vt + ((size_t)bb * 12 + h) * 64 * VS;   // [dv][s]

  __shared__ ushort Ks[128 * 72];     // [kk][dk], pad 64->72
  __shared__ ushort Vs[64 * 136];     // [dv][kk], pad 128->136
  __shared__ ushort Ps[4][16 * 136];  // per-wave P[q][kk], pad 128->136

  const int tid = threadIdx.x, wave = tid >> 6, lane = tid & 63;
  const int quad = lane >> 4, l16 = lane & 15;
  const float LOG2E = 1.44269504f;
  const float NEG_BIG = -1.0e30f;

  const int qtA = pair, qtB = 31 - pair;
  const int qgA = qtA * 64 + wave * 16 + l16;
  const int qgB = qtB * 64 + wave * 16 + l16;
  const int nktA = (qtA >> 1) + 1, nktB = (qtB >> 1) + 1;

  // Q fragments for both strips (B operand of S^T = K*Q^T)
  bf16x8 bqA0 = ld_frag(Qp + (size_t)qgA * DM + quad * 8);
  bf16x8 bqA1 = ld_frag(Qp + (size_t)qgA * DM + 32 + quad * 8);
  bf16x8 bqB0 = ld_frag(Qp + (size_t)qgB * DM + quad * 8);
  bf16x8 bqB1 = ld_frag(Qp + (size_t)qgB * DM + 32 + quad * 8);

  f32x4 accA[4] = {}, accB[4] = {};
  float mA = NEG_BIG, lA = 0.0f, mB = NEG_BIG, lB = 0.0f;

  for (int kt = j; kt < nktB; kt += 2) {
    const int kk0 = kt * 128;
    // stage K tile: chunk c -> row c>>3, col (c&7)*8
#pragma unroll
    for (int i = 0; i < 4; ++i) {
      int c = i * 256 + tid;
      int r = c >> 3, col = (c & 7) * 8;
      *(u4a*)(Ks + r * 72 + col) = *(const u4a*)(Kp + (size_t)(kk0 + r) * DM + col);
    }
    // stage V tile from Vt: chunk c -> dv c>>4, kk (c&15)*8
#pragma unroll
    for (int i = 0; i < 4; ++i) {
      int c = i * 256 + tid;
      int dv = c >> 4, kc = (c & 15) * 8;
      *(u4a*)(Vs + dv * 136 + kc) = *(const u4a*)(Vth + (size_t)dv * VS + kk0 + kc);
    }
    __syncthreads();

    // ---- compute one strip from the staged tile (macro-ish lambda) ----
    auto strip = [&](const bf16x8& bq0, const bf16x8& bq1, f32x4* acc_o,
                     float& m_run, float& l_run, int qg, int nkt) {
      // S^T strip: this wave's 16 q cols x 128 kk rows = 8 tiles
      f32x4 sacc[8] = {};
#pragma unroll
      for (int tt = 0; tt < 8; ++tt) {
        bf16x8 ak0 = ld_frag(Ks + (tt * 16 + l16) * 72 + quad * 8);
        bf16x8 ak1 = ld_frag(Ks + (tt * 16 + l16) * 72 + 32 + quad * 8);
        sacc[tt] = __builtin_amdgcn_mfma_f32_16x16x32_bf16(ak0, bq0, sacc[tt], 0, 0, 0);
        sacc[tt] = __builtin_amdgcn_mfma_f32_16x16x32_bf16(ak1, bq1, sacc[tt], 0, 0, 0);
      }
      // causal mask (diagonal tile only); Q pre-scaled -> no mul
      const bool domask = (kt == nkt - 1);
      float mt = NEG_BIG;
#pragma unroll
      for (int tt = 0; tt < 8; ++tt)
#pragma unroll
        for (int r = 0; r < 4; ++r) {
          float s = sacc[tt][r];
          if (domask) {
            int kkg = kk0 + tt * 16 + quad * 4 + r;
            if (kkg > qg) s = NEG_BIG;
          }
          sacc[tt][r] = s;
          mt = fmaxf(mt, s);
        }
      mt = fmaxf(mt, __shfl_xor(mt, 16, 64));
      mt = fmaxf(mt, __shfl_xor(mt, 32, 64));
      float mnew = fmaxf(m_run, mt);
      float alpha = exp2f((m_run - mnew) * LOG2E);
      float lsum = 0.0f;
#pragma unroll
      for (int tt = 0; tt < 8; ++tt) {
        float p0 = exp2f((sacc[tt][0] - mnew) * LOG2E);
        float p1 = exp2f((sacc[tt][1] - mnew) * LOG2E);
        float p2 = exp2f((sacc[tt][2] - mnew) * LOG2E);
        float p3 = exp2f((sacc[tt][3] - mnew) * LOG2E);
        lsum += (p0 + p1) + (p2 + p3);
        // truncation pack (P in [0,1]: <=2^-8 rel err)
        uint32_t u0 = __builtin_bit_cast(uint32_t, p0);
        uint32_t u1 = __builtin_bit_cast(uint32_t, p1);
        uint32_t u2 = __builtin_bit_cast(uint32_t, p2);
        uint32_t u3 = __builtin_bit_cast(uint32_t, p3);
        u2a pw;
        pw.x = (u0 >> 16) | (u1 & 0xFFFF0000u);
        pw.y = (u2 >> 16) | (u3 & 0xFFFF0000u);
        *(u2a*)(&Ps[wave][l16 * 136 + tt * 16 + quad * 4]) = pw;
      }
      // Ps is per-wave: drain own LDS writes, forbid compile-time reordering.
      asm volatile("s_waitcnt lgkmcnt(0)" ::: "memory");
      lsum += __shfl_xor(lsum, 16, 64);
      lsum += __shfl_xor(lsum, 32, 64);
      l_run = l_run * alpha + lsum;
      m_run = mnew;
      // rescale O: O rows are q = quad*4+reg, alpha lives at lane l16==q
      float ar0 = __shfl(alpha, quad * 4 + 0, 64);
      float ar1 = __shfl(alpha, quad * 4 + 1, 64);
      float ar2 = __shfl(alpha, quad * 4 + 2, 64);
      float ar3 = __shfl(alpha, quad * 4 + 3, 64);
#pragma unroll
      for (int ct = 0; ct < 4; ++ct) {
        acc_o[ct][0] *= ar0; acc_o[ct][1] *= ar1;
        acc_o[ct][2] *= ar2; acc_o[ct][3] *= ar3;
      }
      // O += P*V : A=P from LDS, B=V via Vs[dv][kk]
#pragma unroll
      for (int ks = 0; ks < 4; ++ks) {
        bf16x8 ap = ld_frag(&Ps[wave][l16 * 136 + ks * 32 + quad * 8]);
#pragma unroll
        for (int ct = 0; ct < 4; ++ct) {
          bf16x8 bv = ld_frag(Vs + (size_t)(ct * 16 + l16) * 136 + ks * 32 + quad * 8);
          acc_o[ct] = __builtin_amdgcn_mfma_f32_16x16x32_bf16(ap, bv, acc_o[ct], 0, 0, 0);
        }
      }
    };

    strip(bqB0, bqB1, accB, mB, lB, qgB, nktB);       // always active
    if (kt < nktA)
      strip(bqA0, bqA1, accA, mA, lA, qgA, nktA);     // block-uniform branch
    __syncthreads();   // protect Ks/Vs before next restage
  }

  // store unnormalized partials (bf16 O + per-row m,l) for both strips
  const int base = ((bb * 12 + h) << 5);
  const int r0 = wave * 16 + quad * 4;
  {
    const int slot = (base + qtB) * 2 + j;
    ushort* Os = Opart + (size_t)slot * 4096;
#pragma unroll
    for (int ct = 0; ct < 4; ++ct) {
      int col = ct * 16 + l16;
      Os[(r0 + 0) * 64 + col] = f2b(accB[ct][0]);
      Os[(r0 + 1) * 64 + col] = f2b(accB[ct][1]);
      Os[(r0 + 2) * 64 + col] = f2b(accB[ct][2]);
      Os[(r0 + 3) * 64 + col] = f2b(accB[ct][3]);
    }
    if (quad == 0)
      MLp[(size_t)slot * 64 + wave * 16 + l16] = make_float2(mB, lB);
  }
  {
    const int slot = (base + qtA) * 2 + j;
    ushort* Os = Opart + (size_t)slot * 4096;
#pragma unroll
    for (int ct = 0; ct < 4; ++ct) {
      int col = ct * 16 + l16;
      Os[(r0 + 0) * 64 + col] = f2b(accA[ct][0]);
      Os[(r0 + 1) * 64 + col] = f2b(accA[ct][1]);
      Os[(r0 + 2) * 64 + col] = f2b(accA[ct][2]);
      Os[(r0 + 3) * 64 + col] = f2b(accA[ct][3]);
    }
    if (quad == 0)
      MLp[(size_t)slot * 64 + wave * 16 + l16] = make_float2(mA, lA);
  }
}

// ---------------------------------------------------------------------------
// Combine the two K-parity partials per strip -> Abuf (b, s, h*64) bf16.
// grid 768 (one block per strip), 256 threads, 16 elems/thread.
// An empty partial has m=-1e30, l=0 -> weight exp2(-huge)=0 (no NaN: the
// other partial always exists since every strip has a kt=0... j=0 tile).
// ---------------------------------------------------------------------------
__global__ __launch_bounds__(256) void combine_kernel(
    const ushort* __restrict__ Opart, const float2* __restrict__ MLp,
    ushort* __restrict__ Ab)
{
  const int sid = blockIdx.x;
  const int bb = sid / 384, rem = sid % 384, h = rem >> 5, qt = rem & 31;
  const int t = threadIdx.x, row = t >> 2, cg = (t & 3) * 16;
  float2 ml0 = MLp[(size_t)(sid * 2) * 64 + row];
  float2 ml1 = MLp[(size_t)(sid * 2 + 1) * 64 + row];
  float ms = fmaxf(ml0.x, ml1.x);
  float w0 = exp2f((ml0.x - ms) * 1.44269504f);
  float w1 = exp2f((ml1.x - ms) * 1.44269504f);
  float inv = 1.0f / (ml0.y * w0 + ml1.y * w1);
  w0 *= inv; w1 *= inv;
  const ushort* p0 = Opart + (size_t)(sid * 2) * 4096 + row * 64 + cg;
  ushort* dst = Ab + ((size_t)(bb * 2048 + qt * 64 + row)) * 768 + h * 64 + cg;
#pragma unroll
  for (int g = 0; g < 2; ++g) {
    u4a a = *(const u4a*)(p0 + g * 8);
    u4a b = *(const u4a*)(p0 + 4096 + g * 8);
    u4a o;
    o.x = comb2(a.x, b.x, w0, w1);
    o.y = comb2(a.y, b.y, w0, w1);
    o.z = comb2(a.z, b.z, w0, w1);
    o.w = comb2(a.w, b.w, w0, w1);
    *(u4a*)(dst + g * 8) = o;
  }
}

// ---------------------------------------------------------------------------
extern "C" void kernel_launch(void* const* d_in, const int* in_sizes, int n_in,
                              void* d_out, int out_size, void* d_ws, size_t ws_size,
                              hipStream_t stream) {
  (void)in_sizes; (void)n_in; (void)out_size; (void)ws_size;
  const float* x  = (const float*)d_in[0];
  const float* wq = (const float*)d_in[1];
  const float* wk = (const float*)d_in[2];
  const float* wv = (const float*)d_in[3];
  const float* wo = (const float*)d_in[4];

  const size_t NT = (size_t)4096 * 768;   // tokens x d_model
  const size_t NW = (size_t)768 * 768;
  const size_t NV = (size_t)24 * 64 * VS; // padded Vt
  ushort* xb    = (ushort*)d_ws;          // reused as Abuf after QKV GEMM
  ushort* Qbuf  = xb + NT;
  ushort* Kbuf  = Qbuf + NT;
  ushort* Vt    = Kbuf + NT;              // (b, h, dv, s) stride VS
  ushort* wqb   = Vt + NV;
  ushort* wkb   = wqb + NW;
  ushort* wvb   = wkb + NW;
  ushort* wob   = wvb + NW;
  ushort* Opart = wob + NW;               // 1536 x 64 x 64 bf16
  float2* MLp   = (float2*)(Opart + (size_t)1536 * 4096);  // 1536 x 64
  ushort* Abuf  = xb;                     // lifetime-disjoint reuse

  // fp32 -> bf16 (x + all weights)
  convert_kernel<<<2688, 256, 0, stream>>>(x, wq, wk, wv, wo,
                                           xb, wqb, wkb, wvb, wob);
  // Q/K/V projections (Q pre-scaled; V lands transposed in Vt)
  gemm_qkv<<<dim3(32, 12, 3), 256, 0, stream>>>(
      xb, wqb, wkb, wvb, Qbuf, Kbuf, Vt, 4096, 768, 768);
  // causal flash attention: shared-tile strips, 768 uniform sub-blocks
  attn_kernel<<<dim3(32, 12, 2), 256, 0, stream>>>(Qbuf, Kbuf, Vt, Opart, MLp);
  // merge partials -> Abuf
  combine_kernel<<<768, 256, 0, stream>>>(Opart, MLp, Abuf);
  // output projection (fp32 out)
  gemm_out<<<dim3(64, 12), 256, 0, stream>>>(
      Abuf, wob, (float*)d_out, 4096, 768, 768);
}